// Round 3
// baseline (361.773 us; speedup 1.0000x reference)
//
#include <hip/hip_runtime.h>

typedef __attribute__((ext_vector_type(8))) short short8;
typedef __attribute__((ext_vector_type(4))) short short4_t;
typedef __attribute__((ext_vector_type(4))) float f32x4;
typedef unsigned short ushort_t;

#define DEV __device__ __forceinline__

DEV ushort_t f2bf(float f) {
    unsigned u = __builtin_bit_cast(unsigned, f);
    u = u + 0x7fffu + ((u >> 16) & 1u);   // RNE
    return (ushort_t)(u >> 16);
}

DEV short8 ld8(const ushort_t* p) { return *reinterpret_cast<const short8*>(p); }

// ---------------------------------------------------------------------------
// C[M=4096, N] = A[4096,1024] @ W[1024,N] + bias, output bf16.
// Q/K rows -> outRow as [b,h,s,64]; V half (n>=1024, when outT set) -> outT
// transposed [b,h,64,s] so attention reads V kv-contiguous.
// ---------------------------------------------------------------------------
__global__ __launch_bounds__(256)
void proj_gemm(const float* __restrict__ A, const float* __restrict__ W,
               const float* __restrict__ bias, int N,
               ushort_t* __restrict__ outRow, ushort_t* __restrict__ outT)
{
    __shared__ ushort_t As[128 * 72];  // [row m 0..127][k 0..63], stride 72 (pad)
    __shared__ ushort_t Bt[128 * 72];  // [col n 0..127][k 0..63], stride 72

    const int t = threadIdx.x;
    const int lane = t & 63;
    const int wv = t >> 6;
    const int wr = wv >> 1, wc = wv & 1;
    const int c = lane & 15, g = lane >> 4;
    const int m0 = blockIdx.y * 128, n0 = blockIdx.x * 128;

    f32x4 acc[4][4];
    const f32x4 zero4 = {0.f, 0.f, 0.f, 0.f};
#pragma unroll
    for (int mi = 0; mi < 4; ++mi)
#pragma unroll
        for (int ni = 0; ni < 4; ++ni) acc[mi][ni] = zero4;

    for (int it = 0; it < 16; ++it) {
        const int k0 = it * 64;
        // stage A tile: 128 rows x 64 k (f32 -> bf16)
        {
            const int kq = (t & 15) * 4;
            int r = t >> 4;
#pragma unroll
            for (int rep = 0; rep < 8; ++rep, r += 16) {
                float4 v = *reinterpret_cast<const float4*>(
                    A + (size_t)(m0 + r) * 1024 + k0 + kq);
                ushort_t* dst = &As[r * 72 + kq];
                dst[0] = f2bf(v.x); dst[1] = f2bf(v.y);
                dst[2] = f2bf(v.z); dst[3] = f2bf(v.w);
            }
        }
        // stage W tile (64 k x 128 n), transposed into Bt[n][k]
        {
            const int nq = (t & 31) * 4;
            const int kr = t >> 5;
#pragma unroll
            for (int rep = 0; rep < 8; ++rep) {
                const int k = kr + 8 * rep;
                float4 v = *reinterpret_cast<const float4*>(
                    W + (size_t)(k0 + k) * N + n0 + nq);
                Bt[(nq + 0) * 72 + k] = f2bf(v.x);
                Bt[(nq + 1) * 72 + k] = f2bf(v.y);
                Bt[(nq + 2) * 72 + k] = f2bf(v.z);
                Bt[(nq + 3) * 72 + k] = f2bf(v.w);
            }
        }
        __syncthreads();
#pragma unroll
        for (int kk = 0; kk < 64; kk += 32) {
            short8 afr[4], bfr[4];
#pragma unroll
            for (int mi = 0; mi < 4; ++mi)
                afr[mi] = ld8(&As[(wr * 64 + mi * 16 + c) * 72 + kk + 8 * g]);
#pragma unroll
            for (int ni = 0; ni < 4; ++ni)
                bfr[ni] = ld8(&Bt[(wc * 64 + ni * 16 + c) * 72 + kk + 8 * g]);
#pragma unroll
            for (int mi = 0; mi < 4; ++mi)
#pragma unroll
                for (int ni = 0; ni < 4; ++ni)
                    acc[mi][ni] = __builtin_amdgcn_mfma_f32_16x16x32_bf16(
                        afr[mi], bfr[ni], acc[mi][ni], 0, 0, 0);
        }
        __syncthreads();
    }

    // epilogue: D row = 4*g + j (+16*mi +64*wr), col = c (+16*ni +64*wc)
#pragma unroll
    for (int mi = 0; mi < 4; ++mi) {
#pragma unroll
        for (int ni = 0; ni < 4; ++ni) {
            const int n = n0 + wc * 64 + ni * 16 + c;
            const float bb = bias[n];
#pragma unroll
            for (int j = 0; j < 4; ++j) {
                const int m = m0 + wr * 64 + mi * 16 + 4 * g + j;
                const int b = m >> 11, s = m & 2047;
                const ushort_t val = f2bf(acc[mi][ni][j] + bb);
                if (outT != nullptr && n >= 1024) {
                    const int np = n - 1024;
                    const int hh = np >> 6, d = np & 63;
                    outT[(size_t)((b * 16 + hh) * 64 + d) * 2048 + s] = val;
                } else {
                    const int hh = n >> 6, d = n & 63;
                    outRow[((size_t)((b * 16 + hh) * 2048 + s)) * 64 + d] = val;
                }
            }
        }
    }
}

// ---------------------------------------------------------------------------
// Flash attention per (b,h), fixed-max softmax (scores ~N(0,1), exp safe).
// 8 waves: wq = w&3 owns q rows [qb+32wq,+32); wk = w>>2 owns half the kv.
// QK^T swapped (S^T = mfma(K, Q)) so lane's q = c; P stays in-lane and feeds
// PV^T = mfma(A=V-frag, B=P) with a bijective kv-slot permutation applied to
// BOTH operands (cancels). Partial accv/l/a0/a1 merged by pure addition (LDS).
// m-output rank-2 trick: m = (a0*Wmo0 + a1*Wmo1)/l + bmo.
// ---------------------------------------------------------------------------
__global__ __launch_bounds__(512, 4)
void attn_kernel(const ushort_t* __restrict__ Qr, const ushort_t* __restrict__ Kr,
                 const ushort_t* __restrict__ Vt, const float* __restrict__ cr,
                 const float* __restrict__ Wmo, const float* __restrict__ bmo,
                 float* __restrict__ out)
{
    __shared__ float comb[4 * 64 * 40];   // [wq][lane][40]: 32 accv + 6 stats

    const int t = threadIdx.x;
    const int w = t >> 6, lane = t & 63;
    const int wq = w & 3, wk = w >> 2;
    const int c = lane & 15, g = lane >> 4;

    // XCD swizzle: gid%8 ~ XCD; give each XCD 4 whole (b,h) pairs.
    const int gid = blockIdx.x;
    const int bh = (gid & 7) + 8 * ((gid >> 3) & 3);
    const int xt = gid >> 5;
    const int b = bh >> 4, hh = bh & 15;
    const int qb = xt * 128 + wq * 32;

    const ushort_t* Qh = Qr + (size_t)bh * (2048 * 64);
    const ushort_t* Kh = Kr + (size_t)bh * (2048 * 64);
    const ushort_t* Vh = Vt + (size_t)bh * (64 * 2048);
    const float*   crb = cr + (size_t)b * (2048 * 2);

    short8 bq[2][2];
#pragma unroll
    for (int qt = 0; qt < 2; ++qt)
#pragma unroll
        for (int st = 0; st < 2; ++st)
            bq[qt][st] = ld8(Qh + (size_t)(qb + qt * 16 + c) * 64 + st * 32 + 8 * g);

    f32x4 accv[2][4];
    const f32x4 zero4 = {0.f, 0.f, 0.f, 0.f};
#pragma unroll
    for (int qt = 0; qt < 2; ++qt)
#pragma unroll
        for (int dt = 0; dt < 4; ++dt) accv[qt][dt] = zero4;

    float lst[2] = {0.f, 0.f};
    float a0s[2] = {0.f, 0.f};
    float a1s[2] = {0.f, 0.f};

    const float SCL = 0.18033688011112042f;  // 0.125 * log2(e)
    const int kv0 = wk * 1024;

    for (int kvb = kv0; kvb < kv0 + 1024; kvb += 32) {
        short8 ka[2][2];
#pragma unroll
        for (int ct = 0; ct < 2; ++ct)
#pragma unroll
            for (int st = 0; st < 2; ++st)
                ka[ct][st] = ld8(Kh + (size_t)(kvb + ct * 16 + c) * 64 + st * 32 + 8 * g);
        float4 crv[2][2];
#pragma unroll
        for (int ct = 0; ct < 2; ++ct) {
            const float* cp = crb + (size_t)(kvb + 16 * ct + 4 * g) * 2;
            crv[ct][0] = *reinterpret_cast<const float4*>(cp);
            crv[ct][1] = *reinterpret_cast<const float4*>(cp + 4);
        }

        short8 pa[2];
#pragma unroll
        for (int qt = 0; qt < 2; ++qt) {
            f32x4 sc[2];
#pragma unroll
            for (int ct = 0; ct < 2; ++ct) {
                f32x4 z = zero4;
                z = __builtin_amdgcn_mfma_f32_16x16x32_bf16(ka[ct][0], bq[qt][0], z, 0, 0, 0);
                z = __builtin_amdgcn_mfma_f32_16x16x32_bf16(ka[ct][1], bq[qt][1], z, 0, 0, 0);
                sc[ct] = z;
            }
            // lane holds S^T[kv = kvb+16*ct+4*g+j][q = c]; p = exp(s/8), m == 0
            float lc = lst[qt], a0c = a0s[qt], a1c = a1s[qt];
#pragma unroll
            for (int ct = 0; ct < 2; ++ct) {
                const float cr0[4] = {crv[ct][0].x, crv[ct][0].z, crv[ct][1].x, crv[ct][1].z};
                const float cr1[4] = {crv[ct][0].y, crv[ct][0].w, crv[ct][1].y, crv[ct][1].w};
#pragma unroll
                for (int j = 0; j < 4; ++j) {
                    const float e = exp2f(sc[ct][j] * SCL);
                    lc += e;
                    a0c += e * cr0[j];
                    a1c += e * cr1[j];
                    pa[qt][ct * 4 + j] = (short)f2bf(e);
                }
            }
            lst[qt] = lc; a0s[qt] = a0c; a1s[qt] = a1c;
        }
        // PV^T: D[d][q] += sum_kv V[kv][d] * P[kv][q].
        // B-slot (g,i) carries kv = 16*(i>>2) + 4g + (i&3); A gathers V the
        // same way, so the permutation cancels inside the MFMA.
#pragma unroll
        for (int dt = 0; dt < 4; ++dt) {
            const ushort_t* vp = Vh + (size_t)(dt * 16 + c) * 2048 + kvb + 4 * g;
            const short4_t vlo = *reinterpret_cast<const short4_t*>(vp);
            const short4_t vhi = *reinterpret_cast<const short4_t*>(vp + 16);
            const short8 va = __builtin_shufflevector(vlo, vhi, 0, 1, 2, 3, 4, 5, 6, 7);
            accv[0][dt] = __builtin_amdgcn_mfma_f32_16x16x32_bf16(va, pa[0], accv[0][dt], 0, 0, 0);
            accv[1][dt] = __builtin_amdgcn_mfma_f32_16x16x32_bf16(va, pa[1], accv[1][dt], 0, 0, 0);
        }
    }

    // merge the two kv halves: pure sums (no max bookkeeping)
    float* my = &comb[(wq * 64 + lane) * 40];
    if (wk == 1) {
#pragma unroll
        for (int qt = 0; qt < 2; ++qt)
#pragma unroll
            for (int dt = 0; dt < 4; ++dt)
#pragma unroll
                for (int j = 0; j < 4; ++j) my[qt * 16 + dt * 4 + j] = accv[qt][dt][j];
#pragma unroll
        for (int qt = 0; qt < 2; ++qt) {
            my[32 + qt] = lst[qt]; my[34 + qt] = a0s[qt]; my[36 + qt] = a1s[qt];
        }
    }
    __syncthreads();
    if (wk != 0) return;

#pragma unroll
    for (int qt = 0; qt < 2; ++qt) {
#pragma unroll
        for (int dt = 0; dt < 4; ++dt)
#pragma unroll
            for (int j = 0; j < 4; ++j) accv[qt][dt][j] += my[qt * 16 + dt * 4 + j];
        lst[qt] += my[32 + qt]; a0s[qt] += my[34 + qt]; a1s[qt] += my[36 + qt];
        // reduce stats across g (kv-subsets) -> every lane holds q=c totals
        lst[qt] += __shfl_xor(lst[qt], 16, 64); lst[qt] += __shfl_xor(lst[qt], 32, 64);
        a0s[qt] += __shfl_xor(a0s[qt], 16, 64); a0s[qt] += __shfl_xor(a0s[qt], 32, 64);
        a1s[qt] += __shfl_xor(a1s[qt], 16, 64); a1s[qt] += __shfl_xor(a1s[qt], 32, 64);
    }

    // epilogue: accv[qt][dt] reg j -> q = qb+qt*16+c, d = dt*16+4g+j
#pragma unroll
    for (int qt = 0; qt < 2; ++qt) {
        const int q = qb + qt * 16 + c;
        const float inv = 1.f / lst[qt];
        const float a0 = a0s[qt] * inv, a1 = a1s[qt] * inv;
#pragma unroll
        for (int dt = 0; dt < 4; ++dt) {
            const int d = hh * 64 + dt * 16 + 4 * g;
            const float4 w0 = *reinterpret_cast<const float4*>(Wmo + d);
            const float4 w1 = *reinterpret_cast<const float4*>(Wmo + 1024 + d);
            const float4 bm = *reinterpret_cast<const float4*>(bmo + d);
            const size_t oidx = ((size_t)(b * 2048 + q)) * 1024 + d;
            float4 hv, mv;
            hv.x = accv[qt][dt][0] * inv; hv.y = accv[qt][dt][1] * inv;
            hv.z = accv[qt][dt][2] * inv; hv.w = accv[qt][dt][3] * inv;
            mv.x = a0 * w0.x + a1 * w1.x + bm.x;
            mv.y = a0 * w0.y + a1 * w1.y + bm.y;
            mv.z = a0 * w0.z + a1 * w1.z + bm.z;
            mv.w = a0 * w0.w + a1 * w1.w + bm.w;
            *reinterpret_cast<float4*>(out + oidx) = hv;
            *reinterpret_cast<float4*>(out + 4194304 + oidx) = mv;
        }
    }
}

// ---------------------------------------------------------------------------
extern "C" void kernel_launch(void* const* d_in, const int* in_sizes, int n_in,
                              void* d_out, int out_size, void* d_ws, size_t ws_size,
                              hipStream_t stream)
{
    const float* i1  = (const float*)d_in[0];
    const float* i2  = (const float*)d_in[1];
    const float* cr  = (const float*)d_in[2];
    const float* Wq  = (const float*)d_in[3];
    const float* bq  = (const float*)d_in[4];
    const float* Wkv = (const float*)d_in[5];
    const float* bkv = (const float*)d_in[6];
    const float* Wmo = (const float*)d_in[7];
    const float* bmo = (const float*)d_in[8];
    float* out = (float*)d_out;

    ushort_t* Qr = (ushort_t*)d_ws;          // [2,16,2048,64] bf16
    ushort_t* Kr = Qr + 4194304;             // [2,16,2048,64] bf16
    ushort_t* Vt = Kr + 4194304;             // [2,16,64,2048] bf16

    proj_gemm<<<dim3(8, 32), dim3(256), 0, stream>>>(i1, Wq, bq, 1024, Qr, nullptr);
    proj_gemm<<<dim3(16, 32), dim3(256), 0, stream>>>(i2, Wkv, bkv, 2048, Kr, Vt);
    attn_kernel<<<dim3(512), dim3(512), 0, stream>>>(Qr, Kr, Vt, cr, Wmo, bmo, out);
}

// Round 5
// 358.815 us; speedup vs baseline: 1.0082x; 1.0082x over previous
//
#include <hip/hip_runtime.h>

typedef __attribute__((ext_vector_type(8))) short short8;
typedef __attribute__((ext_vector_type(4))) short short4_t;
typedef __attribute__((ext_vector_type(4))) float f32x4;
typedef unsigned short ushort_t;

#define DEV __device__ __forceinline__

DEV ushort_t f2bf(float f) {
    unsigned u = __builtin_bit_cast(unsigned, f);
    u = u + 0x7fffu + ((u >> 16) & 1u);   // RNE
    return (ushort_t)(u >> 16);
}

DEV short8 ld8(const ushort_t* p) { return *reinterpret_cast<const short8*>(p); }

// ---------------------------------------------------------------------------
// C[M=4096, N] = A[4096,1024] @ W[1024,N] + bias, output bf16.  (r3-proven)
// Q/K rows -> outRow as [b,h,s,64]; V half (n>=1024, when outT set) -> outT
// transposed [b,h,64,s] so attention reads V kv-contiguous.
// ---------------------------------------------------------------------------
__global__ __launch_bounds__(256)
void proj_gemm(const float* __restrict__ A, const float* __restrict__ W,
               const float* __restrict__ bias, int N,
               ushort_t* __restrict__ outRow, ushort_t* __restrict__ outT)
{
    __shared__ ushort_t As[128 * 72];  // [row m 0..127][k 0..63], stride 72 (pad)
    __shared__ ushort_t Bt[128 * 72];  // [col n 0..127][k 0..63], stride 72

    const int t = threadIdx.x;
    const int lane = t & 63;
    const int wv = t >> 6;
    const int wr = wv >> 1, wc = wv & 1;
    const int c = lane & 15, g = lane >> 4;
    const int m0 = blockIdx.y * 128, n0 = blockIdx.x * 128;

    f32x4 acc[4][4];
    const f32x4 zero4 = {0.f, 0.f, 0.f, 0.f};
#pragma unroll
    for (int mi = 0; mi < 4; ++mi)
#pragma unroll
        for (int ni = 0; ni < 4; ++ni) acc[mi][ni] = zero4;

    for (int it = 0; it < 16; ++it) {
        const int k0 = it * 64;
        // stage A tile: 128 rows x 64 k (f32 -> bf16)
        {
            const int kq = (t & 15) * 4;
            int r = t >> 4;
#pragma unroll
            for (int rep = 0; rep < 8; ++rep, r += 16) {
                float4 v = *reinterpret_cast<const float4*>(
                    A + (size_t)(m0 + r) * 1024 + k0 + kq);
                ushort_t* dst = &As[r * 72 + kq];
                dst[0] = f2bf(v.x); dst[1] = f2bf(v.y);
                dst[2] = f2bf(v.z); dst[3] = f2bf(v.w);
            }
        }
        // stage W tile (64 k x 128 n), transposed into Bt[n][k]
        {
            const int nq = (t & 31) * 4;
            const int kr = t >> 5;
#pragma unroll
            for (int rep = 0; rep < 8; ++rep) {
                const int k = kr + 8 * rep;
                float4 v = *reinterpret_cast<const float4*>(
                    W + (size_t)(k0 + k) * N + n0 + nq);
                Bt[(nq + 0) * 72 + k] = f2bf(v.x);
                Bt[(nq + 1) * 72 + k] = f2bf(v.y);
                Bt[(nq + 2) * 72 + k] = f2bf(v.z);
                Bt[(nq + 3) * 72 + k] = f2bf(v.w);
            }
        }
        __syncthreads();
#pragma unroll
        for (int kk = 0; kk < 64; kk += 32) {
            short8 afr[4], bfr[4];
#pragma unroll
            for (int mi = 0; mi < 4; ++mi)
                afr[mi] = ld8(&As[(wr * 64 + mi * 16 + c) * 72 + kk + 8 * g]);
#pragma unroll
            for (int ni = 0; ni < 4; ++ni)
                bfr[ni] = ld8(&Bt[(wc * 64 + ni * 16 + c) * 72 + kk + 8 * g]);
#pragma unroll
            for (int mi = 0; mi < 4; ++mi)
#pragma unroll
                for (int ni = 0; ni < 4; ++ni)
                    acc[mi][ni] = __builtin_amdgcn_mfma_f32_16x16x32_bf16(
                        afr[mi], bfr[ni], acc[mi][ni], 0, 0, 0);
        }
        __syncthreads();
    }

    // epilogue: D row = 4*g + j (+16*mi +64*wr), col = c (+16*ni +64*wc)
#pragma unroll
    for (int mi = 0; mi < 4; ++mi) {
#pragma unroll
        for (int ni = 0; ni < 4; ++ni) {
            const int n = n0 + wc * 64 + ni * 16 + c;
            const float bb = bias[n];
#pragma unroll
            for (int j = 0; j < 4; ++j) {
                const int m = m0 + wr * 64 + mi * 16 + 4 * g + j;
                const int b = m >> 11, s = m & 2047;
                const ushort_t val = f2bf(acc[mi][ni][j] + bb);
                if (outT != nullptr && n >= 1024) {
                    const int np = n - 1024;
                    const int hh = np >> 6, d = np & 63;
                    outT[(size_t)((b * 16 + hh) * 64 + d) * 2048 + s] = val;
                } else {
                    const int hh = n >> 6, d = n & 63;
                    outRow[((size_t)((b * 16 + hh) * 2048 + s)) * 64 + d] = val;
                }
            }
        }
    }
}

// ---------------------------------------------------------------------------
// Flash attention, fixed-max softmax, PV^T, fully register-double-buffered:
// per 32-kv tile: issue ALL next-tile loads (K,V,cr), then compute current.
// ---------------------------------------------------------------------------
DEV void attn_body(const ushort_t* __restrict__ Kh, const ushort_t* __restrict__ Vh,
                   const float* __restrict__ crb, int nxt, int c, int g,
                   const short8 (&bq)[2][2],
                   short8 (&KC)[2][2], short8 (&KN)[2][2],
                   short8 (&VC)[4],    short8 (&VN)[4],
                   float4 (&CC)[2][2], float4 (&CN)[2][2],
                   f32x4 (&accv)[2][4], float (&lst)[2],
                   float (&a0s)[2], float (&a1s)[2])
{
    const f32x4 zero4 = {0.f, 0.f, 0.f, 0.f};
    const float SCL = 0.18033688011112042f;  // (1/8) * log2(e)

    // ---- issue next-tile loads (latency hidden under this body's compute) ----
#pragma unroll
    for (int ct = 0; ct < 2; ++ct)
#pragma unroll
        for (int st = 0; st < 2; ++st)
            KN[ct][st] = ld8(Kh + (size_t)(nxt + ct * 16 + c) * 64 + st * 32 + 8 * g);
#pragma unroll
    for (int dt = 0; dt < 4; ++dt) {
        const ushort_t* vp = Vh + (size_t)(dt * 16 + c) * 2048 + nxt + 4 * g;
        const short4_t vlo = *reinterpret_cast<const short4_t*>(vp);
        const short4_t vhi = *reinterpret_cast<const short4_t*>(vp + 16);
        VN[dt] = __builtin_shufflevector(vlo, vhi, 0, 1, 2, 3, 4, 5, 6, 7);
    }
#pragma unroll
    for (int ct = 0; ct < 2; ++ct) {
        const float* cp = crb + (size_t)(nxt + 16 * ct + 4 * g) * 2;
        CN[ct][0] = *reinterpret_cast<const float4*>(cp);
        CN[ct][1] = *reinterpret_cast<const float4*>(cp + 4);
    }

    // ---- QK^T (swapped): lane holds S^T[kv=16ct+4g+j][q=c] ----
    f32x4 sc[2][2];
#pragma unroll
    for (int qt = 0; qt < 2; ++qt)
#pragma unroll
        for (int ct = 0; ct < 2; ++ct) {
            f32x4 z = zero4;
            z = __builtin_amdgcn_mfma_f32_16x16x32_bf16(KC[ct][0], bq[qt][0], z, 0, 0, 0);
            z = __builtin_amdgcn_mfma_f32_16x16x32_bf16(KC[ct][1], bq[qt][1], z, 0, 0, 0);
            sc[qt][ct] = z;
        }

    // ---- fixed-max softmax + rank-2 cr accumulation ----
    short8 pa[2];
#pragma unroll
    for (int qt = 0; qt < 2; ++qt) {
        float lc = lst[qt], a0c = a0s[qt], a1c = a1s[qt];
#pragma unroll
        for (int ct = 0; ct < 2; ++ct) {
            const float cr0[4] = {CC[ct][0].x, CC[ct][0].z, CC[ct][1].x, CC[ct][1].z};
            const float cr1[4] = {CC[ct][0].y, CC[ct][0].w, CC[ct][1].y, CC[ct][1].w};
#pragma unroll
            for (int j = 0; j < 4; ++j) {
                const float e = exp2f(sc[qt][ct][j] * SCL);
                lc  += e;
                a0c += e * cr0[j];
                a1c += e * cr1[j];
                pa[qt][ct * 4 + j] = (short)f2bf(e);
            }
        }
        lst[qt] = lc; a0s[qt] = a0c; a1s[qt] = a1c;
    }

    // ---- PV^T: A=V gathered in the same kv-slot permutation as P ----
#pragma unroll
    for (int dt = 0; dt < 4; ++dt) {
        accv[0][dt] = __builtin_amdgcn_mfma_f32_16x16x32_bf16(VC[dt], pa[0], accv[0][dt], 0, 0, 0);
        accv[1][dt] = __builtin_amdgcn_mfma_f32_16x16x32_bf16(VC[dt], pa[1], accv[1][dt], 0, 0, 0);
    }
}

__global__ __launch_bounds__(256)
void attn_kernel(const ushort_t* __restrict__ Qr, const ushort_t* __restrict__ Kr,
                 const ushort_t* __restrict__ Vt, const float* __restrict__ cr,
                 const float* __restrict__ Wmo, const float* __restrict__ bmo,
                 float* __restrict__ out)
{
    const int t = threadIdx.x;
    const int w = t >> 6, lane = t & 63;
    const int c = lane & 15, g = lane >> 4;

    // XCD swizzle: gid%8 ~ XCD; each XCD owns 4 whole (b,h) pairs.
    const int gid = blockIdx.x;
    const int bh = (gid & 7) + 8 * ((gid >> 3) & 3);
    const int xt = gid >> 5;
    const int b = bh >> 4, hh = bh & 15;
    const int qb = xt * 128 + w * 32;

    const ushort_t* Qh = Qr + (size_t)bh * (2048 * 64);
    const ushort_t* Kh = Kr + (size_t)bh * (2048 * 64);
    const ushort_t* Vh = Vt + (size_t)bh * (64 * 2048);
    const float*   crb = cr + (size_t)b * (2048 * 2);

    short8 bq[2][2];
#pragma unroll
    for (int qt = 0; qt < 2; ++qt)
#pragma unroll
        for (int st = 0; st < 2; ++st)
            bq[qt][st] = ld8(Qh + (size_t)(qb + qt * 16 + c) * 64 + st * 32 + 8 * g);

    f32x4 accv[2][4];
    const f32x4 zero4 = {0.f, 0.f, 0.f, 0.f};
#pragma unroll
    for (int qt = 0; qt < 2; ++qt)
#pragma unroll
        for (int dt = 0; dt < 4; ++dt) accv[qt][dt] = zero4;

    float lst[2] = {0.f, 0.f};
    float a0s[2] = {0.f, 0.f};
    float a1s[2] = {0.f, 0.f};

    short8 kaA[2][2], kaB[2][2];
    short8 vA[4], vB[4];
    float4 cA[2][2], cB[2][2];

    // prologue: load tile 0 into the A buffers
#pragma unroll
    for (int ct = 0; ct < 2; ++ct)
#pragma unroll
        for (int st = 0; st < 2; ++st)
            kaA[ct][st] = ld8(Kh + (size_t)(ct * 16 + c) * 64 + st * 32 + 8 * g);
#pragma unroll
    for (int dt = 0; dt < 4; ++dt) {
        const ushort_t* vp = Vh + (size_t)(dt * 16 + c) * 2048 + 4 * g;
        const short4_t vlo = *reinterpret_cast<const short4_t*>(vp);
        const short4_t vhi = *reinterpret_cast<const short4_t*>(vp + 16);
        vA[dt] = __builtin_shufflevector(vlo, vhi, 0, 1, 2, 3, 4, 5, 6, 7);
    }
#pragma unroll
    for (int ct = 0; ct < 2; ++ct) {
        const float* cp = crb + (size_t)(16 * ct + 4 * g) * 2;
        cA[ct][0] = *reinterpret_cast<const float4*>(cp);
        cA[ct][1] = *reinterpret_cast<const float4*>(cp + 4);
    }

    for (int kvb = 0; kvb < 2048; kvb += 64) {
        attn_body(Kh, Vh, crb, kvb + 32, c, g, bq,
                  kaA, kaB, vA, vB, cA, cB, accv, lst, a0s, a1s);
        attn_body(Kh, Vh, crb, (kvb + 64) & 2047, c, g, bq,
                  kaB, kaA, vB, vA, cB, cA, accv, lst, a0s, a1s);
    }

    // reduce stats across g (kv-subsets): every lane gets q=c totals
#pragma unroll
    for (int qt = 0; qt < 2; ++qt) {
        lst[qt] += __shfl_xor(lst[qt], 16, 64); lst[qt] += __shfl_xor(lst[qt], 32, 64);
        a0s[qt] += __shfl_xor(a0s[qt], 16, 64); a0s[qt] += __shfl_xor(a0s[qt], 32, 64);
        a1s[qt] += __shfl_xor(a1s[qt], 16, 64); a1s[qt] += __shfl_xor(a1s[qt], 32, 64);
    }

    // epilogue: accv[qt][dt] reg j -> q = qb+qt*16+c, d = dt*16+4g+j
#pragma unroll
    for (int qt = 0; qt < 2; ++qt) {
        const int q = qb + qt * 16 + c;
        const float inv = 1.f / lst[qt];
        const float a0 = a0s[qt] * inv, a1 = a1s[qt] * inv;
#pragma unroll
        for (int dt = 0; dt < 4; ++dt) {
            const int d = hh * 64 + dt * 16 + 4 * g;
            const float4 w0 = *reinterpret_cast<const float4*>(Wmo + d);
            const float4 w1 = *reinterpret_cast<const float4*>(Wmo + 1024 + d);
            const float4 bm = *reinterpret_cast<const float4*>(bmo + d);
            const size_t oidx = ((size_t)(b * 2048 + q)) * 1024 + d;
            float4 hv, mv;
            hv.x = accv[qt][dt][0] * inv; hv.y = accv[qt][dt][1] * inv;
            hv.z = accv[qt][dt][2] * inv; hv.w = accv[qt][dt][3] * inv;
            mv.x = a0 * w0.x + a1 * w1.x + bm.x;
            mv.y = a0 * w0.y + a1 * w1.y + bm.y;
            mv.z = a0 * w0.z + a1 * w1.z + bm.z;
            mv.w = a0 * w0.w + a1 * w1.w + bm.w;
            *reinterpret_cast<float4*>(out + oidx) = hv;
            *reinterpret_cast<float4*>(out + 4194304 + oidx) = mv;
        }
    }
}

// ---------------------------------------------------------------------------
extern "C" void kernel_launch(void* const* d_in, const int* in_sizes, int n_in,
                              void* d_out, int out_size, void* d_ws, size_t ws_size,
                              hipStream_t stream)
{
    const float* i1  = (const float*)d_in[0];
    const float* i2  = (const float*)d_in[1];
    const float* cr  = (const float*)d_in[2];
    const float* Wq  = (const float*)d_in[3];
    const float* bq  = (const float*)d_in[4];
    const float* Wkv = (const float*)d_in[5];
    const float* bkv = (const float*)d_in[6];
    const float* Wmo = (const float*)d_in[7];
    const float* bmo = (const float*)d_in[8];
    float* out = (float*)d_out;

    ushort_t* Qr = (ushort_t*)d_ws;          // [2,16,2048,64] bf16 (8 MB)
    ushort_t* Kr = Qr + 4194304;             // [2,16,2048,64] bf16 (8 MB)
    ushort_t* Vt = Kr + 4194304;             // [2,16,64,2048] bf16 (8 MB)

    proj_gemm<<<dim3(8, 32), dim3(256), 0, stream>>>(i1, Wq, bq, 1024, Qr, nullptr);
    proj_gemm<<<dim3(16, 32), dim3(256), 0, stream>>>(i2, Wkv, bkv, 2048, Kr, Vt);
    attn_kernel<<<dim3(512), dim3(256), 0, stream>>>(Qr, Kr, Vt, cr, Wmo, bmo, out);
}